// Round 2
// baseline (1129.874 us; speedup 1.0000x reference)
//
#include <hip/hip_runtime.h>

#define BB 4
#define HH 352
#define WW 1216
#define HW (HH * WW)
#define NPIX (BB * HW)   // 1,712,128

// ---------------------------------------------------------------------------
// Kernel A: 3x3 conv (8 -> 24 ch, zero pad) + TGASS affinity; emits per-tap
// tables in plane-major layout [9][NPIX]:
//   affp : modulation weight
//   ysrp : ky + dy   (relative sample row offset)
//   xsrp : kx + dx   (relative sample col offset)
// Channel mapping (verified vs reference reshape semantics):
//   neighbor n: dy = conv_out[2n], dx = conv_out[2n+1]  (pairs interleaved!)
//   affinity:   conv_out[16 + n]
// Tap mapping: prop taps 0..3 -> neighbors 0..3, tap 4 = reference (0,0),
// taps 5..8 -> neighbors 4..7.
// ---------------------------------------------------------------------------
__global__ __launch_bounds__(256) void conv_tgass_kernel(
    const float* __restrict__ guid, const float* __restrict__ w,
    const float* __restrict__ bias, const float* __restrict__ scale_p,
    float* __restrict__ affp, float* __restrict__ ysrp, float* __restrict__ xsrp)
{
    int idx = blockIdx.x * blockDim.x + threadIdx.x;
    if (idx >= NPIX) return;
    int x = idx % WW;
    int t = idx / WW;
    int y = t % HH;
    int b = t / HH;
    const float* gb = guid + (size_t)b * 8 * HW;

    float acc[24];
#pragma unroll
    for (int o = 0; o < 24; ++o) acc[o] = bias[o];

    for (int c = 0; c < 8; ++c) {
        const float* gc = gb + (size_t)c * HW;
#pragma unroll
        for (int t9 = 0; t9 < 9; ++t9) {
            int dy = t9 / 3 - 1, dx = t9 % 3 - 1;
            int yy = y + dy, xx = x + dx;
            float v = 0.f;
            if (yy >= 0 && yy < HH && xx >= 0 && xx < WW)
                v = gc[yy * WW + xx];
            // w is thread-uniform -> scalar loads
#pragma unroll
            for (int o = 0; o < 24; ++o)
                acc[o] = fmaf(w[o * 72 + c * 9 + t9], v, acc[o]);
        }
    }

    // TGASS: tanh / scale, L1-normalize (clamped >= 1), ref = 1 - sum
    float sc = scale_p[0] + 1e-8f;
    float a[8];
    float asum = 1e-4f;
#pragma unroll
    for (int t8 = 0; t8 < 8; ++t8) {
        a[t8] = tanhf(acc[16 + t8]) / sc;
        asum += fabsf(a[t8]);
    }
    asum = fmaxf(asum, 1.0f);
    float ssum = 0.f;
#pragma unroll
    for (int t8 = 0; t8 < 8; ++t8) { a[t8] = a[t8] / asum; ssum += a[t8]; }
    float aref = 1.0f - ssum;

#pragma unroll
    for (int k = 0; k < 9; ++k) {
        float ky = (float)(k / 3 - 1), kx = (float)(k % 3 - 1);
        float ak, yr, xr;
        if (k == 4) { ak = aref; yr = 0.f; xr = 0.f; }
        else {
            int t8 = (k < 4) ? k : k - 1;
            ak = a[t8];
            yr = ky + acc[2 * t8];       // dy = conv_out[2n]
            xr = kx + acc[2 * t8 + 1];   // dx = conv_out[2n+1]
        }
        size_t off = (size_t)k * NPIX + (size_t)idx;
        affp[off] = ak;
        ysrp[off] = yr;
        xsrp[off] = xr;
    }
}

// ---------------------------------------------------------------------------
// Kernel B: one propagation step. out = [conf *] sum_k aff_k * bilinear(featc)
// Zero outside bounds, per-corner validity (DCNv2 semantics).
// ---------------------------------------------------------------------------
__device__ __forceinline__ float fetch_px(const float* __restrict__ f, int yi, int xi)
{
    return (yi >= 0 && yi < HH && xi >= 0 && xi < WW) ? f[yi * WW + xi] : 0.f;
}

template <bool MULCONF>
__global__ __launch_bounds__(256) void prop_step_kernel(
    const float* __restrict__ featc, const float* __restrict__ affp,
    const float* __restrict__ ysrp, const float* __restrict__ xsrp,
    const float* __restrict__ conf, float* __restrict__ outp)
{
    int idx = blockIdx.x * blockDim.x + threadIdx.x;
    if (idx >= NPIX) return;
    int x = idx % WW;
    int t = idx / WW;
    int y = t % HH;
    int b = t / HH;
    const float* f = featc + (size_t)b * HW;

    float res = 0.f;
#pragma unroll
    for (int k = 0; k < 9; ++k) {
        size_t off = (size_t)k * NPIX + (size_t)idx;
        float ak = affp[off];
        float ys = (float)y + ysrp[off];
        float xs = (float)x + xsrp[off];
        float y0f = floorf(ys), x0f = floorf(xs);
        float wy1 = ys - y0f, wx1 = xs - x0f;
        float wy0 = 1.f - wy1, wx0 = 1.f - wx1;
        int y0 = (int)y0f, x0 = (int)x0f;
        float v00 = fetch_px(f, y0, x0);
        float v01 = fetch_px(f, y0, x0 + 1);
        float v10 = fetch_px(f, y0 + 1, x0);
        float v11 = fetch_px(f, y0 + 1, x0 + 1);
        float sv = wy0 * (wx0 * v00 + wx1 * v01) + wy1 * (wx0 * v10 + wx1 * v11);
        res = fmaf(ak, sv, res);
    }
    if (MULCONF) res *= conf[idx];
    outp[idx] = res;
}

// featc0 = feat_init * conf
__global__ __launch_bounds__(256) void mul_kernel(
    const float* __restrict__ a, const float* __restrict__ c, float* __restrict__ o)
{
    int i = blockIdx.x * blockDim.x + threadIdx.x;
    if (i < NPIX) o[i] = a[i] * c[i];
}

extern "C" void kernel_launch(void* const* d_in, const int* in_sizes, int n_in,
                              void* d_out, int out_size, void* d_ws, size_t ws_size,
                              hipStream_t stream)
{
    const float* feat_init  = (const float*)d_in[0];
    const float* guidance   = (const float*)d_in[1];
    const float* confidence = (const float*)d_in[2];
    const float* w_oa       = (const float*)d_in[3];
    const float* b_oa       = (const float*)d_in[4];
    const float* aff_scale  = (const float*)d_in[5];
    float* out = (float*)d_out;

    // Workspace layout (floats): aff[9N] | ysr[9N] | xsr[9N] | fc0[N] | fc1[N]
    const size_t N = (size_t)NPIX;
    float* aff = (float*)d_ws;
    float* ysr = aff + 9 * N;
    float* xsr = ysr + 9 * N;
    float* fc0 = xsr + 9 * N;
    float* fc1 = fc0 + N;

    const int threads = 256;
    const int blocks = (NPIX + threads - 1) / threads;

    mul_kernel<<<blocks, threads, 0, stream>>>(feat_init, confidence, fc0);
    conv_tgass_kernel<<<blocks, threads, 0, stream>>>(
        guidance, w_oa, b_oa, aff_scale, aff, ysr, xsr);

    float* bufs[2] = {fc0, fc1};
    const int T = 18;
    for (int i = 0; i < T; ++i) {
        const float* src = bufs[i & 1];
        if (i < T - 1) {
            float* dst = bufs[(i + 1) & 1];
            prop_step_kernel<true><<<blocks, threads, 0, stream>>>(
                src, aff, ysr, xsr, confidence, dst);
        } else {
            prop_step_kernel<false><<<blocks, threads, 0, stream>>>(
                src, aff, ysr, xsr, confidence, out);
        }
    }
}